// Round 7
// baseline (1397.817 us; speedup 1.0000x reference)
//
#include <hip/hip_runtime.h>

#define NN   50000
#define EE   800000
#define INC  128
#define OUTC 256
#define HALF 128
#define NREL 6
#define NCELL (NN * NREL)   // 300000
#define NPAD 50048          // 391*128

typedef __attribute__((ext_vector_type(4))) short s16x4;
typedef __attribute__((ext_vector_type(8))) short bf16x8;
typedef __attribute__((ext_vector_type(4))) float f32x4;

__device__ __forceinline__ float b2f(short b) {
    unsigned u = ((unsigned)(unsigned short)b) << 16;
    return __uint_as_float(u);
}
__device__ __forceinline__ short f2b(float f) {
    unsigned u = __float_as_uint(f);
    unsigned r = (u + 0x7fffu + ((u >> 16) & 1u)) >> 16;   // RNE
    return (short)r;
}

__device__ __forceinline__ void gload16(const void* g, void* l) {
    __builtin_amdgcn_global_load_lds(
        (const __attribute__((address_space(1))) void*)g,
        (__attribute__((address_space(3))) void*)l, 16, 0, 0);
}

// ---------------- CSR build ----------------
__global__ __launch_bounds__(256) void count_k(const int* __restrict__ dst,
                                               const int* __restrict__ et,
                                               int* __restrict__ cnt) {
    int e = blockIdx.x * 256 + threadIdx.x;
    if (e < EE) atomicAdd(&cnt[dst[e] * NREL + et[e]], 1);
}

__global__ __launch_bounds__(256) void scanA_k(const int* __restrict__ cnt,
                                               int* __restrict__ off,
                                               int* __restrict__ bsum, int n) {
    __shared__ int sh[256];
    int t = threadIdx.x;
    int base = blockIdx.x * 512 + t * 2;
    int v0 = (base < n) ? cnt[base] : 0;
    int v1 = (base + 1 < n) ? cnt[base + 1] : 0;
    int s = v0 + v1;
    sh[t] = s; __syncthreads();
    for (int o = 1; o < 256; o <<= 1) {
        int u = (t >= o) ? sh[t - o] : 0;
        __syncthreads();
        sh[t] += u;
        __syncthreads();
    }
    int excl = sh[t] - s;
    if (base < n)     off[base]     = excl;
    if (base + 1 < n) off[base + 1] = excl + v0;
    if (t == 255) bsum[blockIdx.x] = sh[255];
}

__global__ __launch_bounds__(1024) void scanB_k(int* __restrict__ bsum, int nb) {
    __shared__ int sh[1024];
    int t = threadIdx.x;
    int s = (t < nb) ? bsum[t] : 0;
    sh[t] = s; __syncthreads();
    for (int o = 1; o < 1024; o <<= 1) {
        int u = (t >= o) ? sh[t - o] : 0;
        __syncthreads();
        sh[t] += u;
        __syncthreads();
    }
    if (t < nb) bsum[t] = sh[t] - s;
}

__global__ __launch_bounds__(256) void scanC_k(int* __restrict__ off,
                                               const int* __restrict__ bsum, int n) {
    int i = blockIdx.x * 256 + threadIdx.x;
    if (i < n) off[i] += bsum[i >> 9];
    if (i == 0) off[n] = EE;
}

__global__ __launch_bounds__(256) void copyint_k(const int* __restrict__ a,
                                                 int* __restrict__ b, int n) {
    int i = blockIdx.x * 256 + threadIdx.x;
    if (i < n) b[i] = a[i];
}

__global__ __launch_bounds__(256) void fill_k(const int* __restrict__ src,
                                              const int* __restrict__ dst,
                                              const int* __restrict__ et,
                                              int* __restrict__ cur,
                                              int* __restrict__ es) {
    int e = blockIdx.x * 256 + threadIdx.x;
    if (e < EE) {
        int key = dst[e] * NREL + et[e];
        int p = atomicAdd(&cur[key], 1);
        es[p] = src[e];
    }
}

// ---------------- casts ----------------
__global__ __launch_bounds__(256) void cast_x_k(const float* __restrict__ x,
                                                short* __restrict__ xb, int n4) {
    int i = blockIdx.x * 256 + threadIdx.x;
    if (i < n4) {
        float4 v = ((const float4*)x)[i];
        s16x4 o;
        o[0] = f2b(v.x); o[1] = f2b(v.y); o[2] = f2b(v.z); o[3] = f2b(v.w);
        ((s16x4*)xb)[i] = o;
    }
}

// WT[Ncols][Ktot] = [root; W]^T  (bf16) — R0-verified layout.
// k < K0 -> root[k][n]; else W[(k-K0)/Din][ (k-K0)%Din ][n] via flat (k-K0)*Ncols.
__global__ __launch_bounds__(256) void wtcat_k(const float* __restrict__ root,
                                               const float* __restrict__ W,
                                               int K0, int Ktot, int Ncols,
                                               short* __restrict__ WT) {
    int i = blockIdx.x * 256 + threadIdx.x;
    if (i >= Ncols * Ktot) return;
    int n = i / Ktot, k = i - n * Ktot;
    float v = (k < K0) ? root[(size_t)k * Ncols + n]
                       : W[(size_t)(k - K0) * Ncols + n];
    WT[(size_t)n * Ktot + k] = f2b(v);
}

// ---------------- fused gather-GEMM (dual-problem) ----------------
// C[M,Ncols] = [A0 | AG] @ WT^T (+bias,+relu), where AG[i, rel*D + c] =
// mean_{j in N_rel(i)} X[j, c] is NEVER materialized: for K-steps past Ksplit
// the A-tile is computed in-kernel (CSR edge loop over L2/L3-resident X) and
// ds_write'n into the swizzled LDS slots.  Problem 2 (encoder) sets Kt==Ks
// -> pure-GEMM path.  Self region + B staged via global_load_lds as before.
// Epilogue: LDS slab -> full-line 16B/lane stores (R4-verified).
#define ACH(R, q) ((((R) << 2) | ((q) ^ ((R) & 3) ^ (((R) >> 2) & 1))) * 8)

__global__ __launch_bounds__(256) void fgemm_k(
    const short* __restrict__ A01, const short* __restrict__ X1,
    const short* __restrict__ B1, int Kt1, int Ks1, int dsh1,
    const float* __restrict__ bias1, int relu1,
    short* __restrict__ Cb1, int ldcb1, float* __restrict__ Cf1, int ldcf1,
    const short* __restrict__ A02, const short* __restrict__ X2,
    const short* __restrict__ B2, int Kt2, int Ks2, int dsh2,
    const float* __restrict__ bias2, int relu2,
    short* __restrict__ Cb2, int ldcb2, float* __restrict__ Cf2, int ldcf2,
    const int* __restrict__ off, const int* __restrict__ es,
    int M, int nby1) {
    __shared__ __align__(16) char smem[16384];
    short* As = (short*)smem;                // [128*32] bf16 (swizzled chunks)
    short* Bs = As + 128 * 32;               // [128*32] bf16
    const int tid = threadIdx.x;
    const int wave = tid >> 6, lane = tid & 63;
    const int wm = (wave & 1) * 64, wn = (wave >> 1) * 64;
    const int l16 = lane & 15, quad = lane >> 4;
    const int bm = blockIdx.x * 128;

    const short *A0, *X, *BT; const float* bias;
    int Kt, Ks, dsh, relu; short* Cb; int ldcb; float* Cf; int ldcf; int bn;
    if ((int)blockIdx.y < nby1) {
        A0 = A01; X = X1; BT = B1; Kt = Kt1; Ks = Ks1; dsh = dsh1;
        bias = bias1; relu = relu1; Cb = Cb1; ldcb = ldcb1; Cf = Cf1; ldcf = ldcf1;
        bn = blockIdx.y * 128;
    } else {
        A0 = A02; X = X2; BT = B2; Kt = Kt2; Ks = Ks2; dsh = dsh2;
        bias = bias2; relu = relu2; Cb = Cb2; ldcb = ldcb2; Cf = Cf2; ldcf = ldcf2;
        bn = (blockIdx.y - nby1) * 128;
    }

    // staging slots (linear DMA dest == tid order), pre-swizzled source coords
    const int s0 = tid, s1 = tid + 256;
    const int r0 = s0 >> 2, c0 = (s0 & 3) ^ (r0 & 3) ^ ((r0 >> 2) & 1);
    const int r1 = s1 >> 2, c1 = (s1 & 3) ^ (r1 & 3) ^ ((r1 >> 2) & 1);

    f32x4 acc[4][4];
    #pragma unroll
    for (int i = 0; i < 4; ++i)
        #pragma unroll
        for (int j = 0; j < 4; ++j)
            acc[i][j] = (f32x4)0.f;

    const int Dm = (1 << dsh) - 1;
    for (int k0 = 0; k0 < Kt; k0 += 32) {
        if (k0 < Ks) {
            gload16(A0 + (size_t)(bm + r0) * Ks + k0 + c0 * 8, As + s0 * 8);
            gload16(A0 + (size_t)(bm + r1) * Ks + k0 + c1 * 8, As + s1 * 8);
        }
        gload16(BT + (size_t)(bn + r0) * Kt + k0 + c0 * 8, Bs + s0 * 8);
        gload16(BT + (size_t)(bn + r1) * Kt + k0 + c1 * 8, Bs + s1 * 8);
        if (k0 >= Ks) {
            // compute A-tile: mean-gather from X (L2/L3-resident source)
            int koff = k0 - Ks;
            int rel = koff >> dsh, cbx = koff & Dm;
            int q = tid & 3, rbase = tid >> 2;
            const short* Xb = X + cbx + q * 8;
            #pragma unroll
            for (int pass = 0; pass < 2; ++pass) {
                int row = pass * 64 + rbase;
                int node = bm + row;
                int beg = 0, end = 0;
                if (node < NN) {
                    int cell = node * NREL + rel;
                    beg = off[cell]; end = off[cell + 1];
                }
                float a0 = 0.f, a1 = 0.f, a2 = 0.f, a3 = 0.f;
                float a4 = 0.f, a5 = 0.f, a6 = 0.f, a7 = 0.f;
                int j = beg;
                for (; j + 1 < end; j += 2) {
                    bf16x8 v = *(const bf16x8*)(Xb + ((size_t)es[j] << dsh));
                    bf16x8 w = *(const bf16x8*)(Xb + ((size_t)es[j + 1] << dsh));
                    a0 += b2f(v[0]) + b2f(w[0]);
                    a1 += b2f(v[1]) + b2f(w[1]);
                    a2 += b2f(v[2]) + b2f(w[2]);
                    a3 += b2f(v[3]) + b2f(w[3]);
                    a4 += b2f(v[4]) + b2f(w[4]);
                    a5 += b2f(v[5]) + b2f(w[5]);
                    a6 += b2f(v[6]) + b2f(w[6]);
                    a7 += b2f(v[7]) + b2f(w[7]);
                }
                if (j < end) {
                    bf16x8 v = *(const bf16x8*)(Xb + ((size_t)es[j] << dsh));
                    a0 += b2f(v[0]); a1 += b2f(v[1]);
                    a2 += b2f(v[2]); a3 += b2f(v[3]);
                    a4 += b2f(v[4]); a5 += b2f(v[5]);
                    a6 += b2f(v[6]); a7 += b2f(v[7]);
                }
                float inv = (end > beg) ? 1.f / (float)(end - beg) : 0.f;
                bf16x8 o;
                o[0] = f2b(a0 * inv); o[1] = f2b(a1 * inv);
                o[2] = f2b(a2 * inv); o[3] = f2b(a3 * inv);
                o[4] = f2b(a4 * inv); o[5] = f2b(a5 * inv);
                o[6] = f2b(a6 * inv); o[7] = f2b(a7 * inv);
                *(bf16x8*)&As[ACH(row, q)] = o;     // swizzled reg-staged write
            }
        }
        __syncthreads();
        bf16x8 af[4], bf[4];
        #pragma unroll
        for (int mt = 0; mt < 4; ++mt)
            af[mt] = *(const bf16x8*)&As[ACH(wm + mt * 16 + l16, quad)];
        #pragma unroll
        for (int nt = 0; nt < 4; ++nt)
            bf[nt] = *(const bf16x8*)&Bs[ACH(wn + nt * 16 + l16, quad)];
        #pragma unroll
        for (int mt = 0; mt < 4; ++mt)
            #pragma unroll
            for (int nt = 0; nt < 4; ++nt)
                acc[mt][nt] = __builtin_amdgcn_mfma_f32_16x16x32_bf16(
                    af[mt], bf[nt], acc[mt][nt], 0, 0, 0);
        __syncthreads();
    }

    float bv[4];
    #pragma unroll
    for (int nt = 0; nt < 4; ++nt)
        bv[nt] = bias ? bias[bn + wn + nt * 16 + l16] : 0.f;

    // slab row: sr = (wave&1)*16 + quad*4 + r  <->  grow = bm + (sr>>4)*64 + mt*16 + (sr&15)
    if (Cb) {
        short* Es = (short*)smem;            // [32][128] bf16 slab
        #pragma unroll
        for (int mt = 0; mt < 4; ++mt) {
            __syncthreads();
            int srb = (wave & 1) * 16 + quad * 4;
            #pragma unroll
            for (int nt = 0; nt < 4; ++nt) {
                int sc = wn + nt * 16 + l16;
                #pragma unroll
                for (int r = 0; r < 4; ++r) {
                    float v = acc[mt][nt][r] + bv[nt];
                    if (relu) v = fmaxf(v, 0.f);
                    Es[(srb + r) * 128 + sc] = f2b(v);
                }
            }
            __syncthreads();
            #pragma unroll
            for (int h = 0; h < 2; ++h) {
                int c = tid + h * 256;       // chunk 0..511: 32 rows x 16 chunks
                int rr = c >> 4, cc = c & 15;
                int grow = bm + (rr >> 4) * 64 + mt * 16 + (rr & 15);
                if (grow < M)
                    *(bf16x8*)(Cb + (size_t)grow * ldcb + bn + cc * 8) =
                        *(const bf16x8*)&Es[rr * 128 + cc * 8];
            }
        }
    } else {
        float* Ef = (float*)smem;            // [32][128] f32 slab (16 KB)
        #pragma unroll
        for (int mt = 0; mt < 4; ++mt) {
            __syncthreads();
            int srb = (wave & 1) * 16 + quad * 4;
            #pragma unroll
            for (int nt = 0; nt < 4; ++nt) {
                int sc = wn + nt * 16 + l16;
                #pragma unroll
                for (int r = 0; r < 4; ++r) {
                    float v = acc[mt][nt][r] + bv[nt];
                    if (relu) v = fmaxf(v, 0.f);
                    Ef[(srb + r) * 128 + sc] = v;
                }
            }
            __syncthreads();
            #pragma unroll
            for (int h = 0; h < 4; ++h) {
                int c = tid + h * 256;       // chunk 0..1023: 32 rows x 32 chunks
                int rr = c >> 5, cc = c & 31;
                int grow = bm + (rr >> 4) * 64 + mt * 16 + (rr & 15);
                if (grow < M)
                    *(float4*)(Cf + (size_t)grow * ldcf + bn + cc * 4) =
                        *(const float4*)&Ef[rr * 128 + cc * 4];
            }
        }
    }
}

// ---------------- host ----------------
extern "C" void kernel_launch(void* const* d_in, const int* in_sizes, int n_in,
                              void* d_out, int out_size, void* d_ws, size_t ws_size,
                              hipStream_t stream) {
    const float* x      = (const float*)d_in[0];
    const int*   ei     = (const int*)d_in[1];
    const int*   srcv   = ei;
    const int*   dstv   = ei + EE;
    const int*   et     = (const int*)d_in[2];
    const float* enc_w0 = (const float*)d_in[3];
    const float* enc_b0 = (const float*)d_in[4];
    const float* enc_w1 = (const float*)d_in[5];
    const float* enc_b1 = (const float*)d_in[6];
    const float* enc_w2 = (const float*)d_in[7];
    const float* enc_b2 = (const float*)d_in[8];
    const float* W1     = (const float*)d_in[9];
    const float* root1  = (const float*)d_in[10];
    const float* b1     = (const float*)d_in[11];
    const float* W2     = (const float*)d_in[12];
    const float* root2  = (const float*)d_in[13];
    const float* b2     = (const float*)d_in[14];
    const float* W3     = (const float*)d_in[15];
    const float* root3  = (const float*)d_in[16];
    const float* b3     = (const float*)d_in[17];
    float* out = (float*)d_out;

    char* p = (char*)d_ws;
    auto alloc = [&](size_t bytes) -> char* {
        char* r = p; p += (bytes + 255) & ~(size_t)255; return r;
    };
    short* xb  = (short*)alloc((size_t)NPAD * INC * 2);
    short* g1  = (short*)alloc((size_t)NPAD * OUTC * 2);
    short* g2  = (short*)alloc((size_t)NPAD * OUTC * 2);
    short* e1  = (short*)alloc((size_t)NPAD * OUTC * 2);
    short* e2  = (short*)alloc((size_t)NPAD * OUTC * 2);
    short* WT1 = (short*)alloc((size_t)OUTC * 896 * 2);    // [root1; W1]^T
    short* WT2 = (short*)alloc((size_t)OUTC * 1792 * 2);   // [root2; W2]^T
    short* WT3 = (short*)alloc((size_t)HALF * 1792 * 2);   // [root3; W3]^T
    short* ET0 = (short*)alloc((size_t)OUTC * INC * 2);
    short* ET1 = (short*)alloc((size_t)OUTC * OUTC * 2);
    short* ET2 = (short*)alloc((size_t)HALF * OUTC * 2);
    int* CNT  = (int*)alloc((size_t)NCELL * 4);
    int* OFF  = (int*)alloc((size_t)(NCELL + 1) * 4);
    int* CUR  = (int*)alloc((size_t)NCELL * 4);
    int* ES   = (int*)alloc((size_t)EE * 4);
    int* BSUM = (int*)alloc(1024 * 4);

    // ---- CSR build (once; edge structure shared by all 3 layers)
    hipMemsetAsync(CNT, 0, (size_t)NCELL * 4, stream);
    count_k<<<EE / 256, 256, 0, stream>>>(dstv, et, CNT);
    int nbA = (NCELL + 511) / 512;
    scanA_k<<<nbA, 256, 0, stream>>>(CNT, OFF, BSUM, NCELL);
    scanB_k<<<1, 1024, 0, stream>>>(BSUM, nbA);
    scanC_k<<<(NCELL + 255) / 256, 256, 0, stream>>>(OFF, BSUM, NCELL);
    copyint_k<<<(NCELL + 255) / 256, 256, 0, stream>>>(OFF, CUR, NCELL);
    fill_k<<<EE / 256, 256, 0, stream>>>(srcv, dstv, et, CUR, ES);

    // ---- weight transposes + input cast
    cast_x_k<<<(NN * INC / 4 + 255) / 256, 256, 0, stream>>>(x, xb, NN * INC / 4);
    wtcat_k<<<(OUTC * 896 + 255) / 256, 256, 0, stream>>>(root1, W1, INC, 896, OUTC, WT1);
    wtcat_k<<<(OUTC * 1792 + 255) / 256, 256, 0, stream>>>(root2, W2, OUTC, 1792, OUTC, WT2);
    wtcat_k<<<(HALF * 1792 + 255) / 256, 256, 0, stream>>>(root3, W3, OUTC, 1792, HALF, WT3);
    wtcat_k<<<(OUTC * INC + 255) / 256, 256, 0, stream>>>(enc_w0, nullptr, INC, INC, OUTC, ET0);
    wtcat_k<<<(OUTC * OUTC + 255) / 256, 256, 0, stream>>>(enc_w1, nullptr, OUTC, OUTC, OUTC, ET1);
    wtcat_k<<<(HALF * OUTC + 255) / 256, 256, 0, stream>>>(enc_w2, nullptr, OUTC, OUTC, HALF, ET2);

    // ---- batch 1: conv1 fused (N=256, Kt=896, gather from xb D=128) | enc1
    fgemm_k<<<dim3(391, 4), 256, 0, stream>>>(
        xb, xb, WT1, 896, INC, 7, b1, 1, g1, OUTC, nullptr, 0,
        xb, nullptr, ET0, INC, INC, 7, enc_b0, 1, e1, OUTC, nullptr, 0,
        OFF, ES, NN, 2);
    // ---- batch 2: conv2 fused (N=256, Kt=1792, gather from g1 D=256) | enc2
    fgemm_k<<<dim3(391, 4), 256, 0, stream>>>(
        g1, g1, WT2, 1792, OUTC, 8, b2, 1, g2, OUTC, nullptr, 0,
        e1, nullptr, ET1, OUTC, OUTC, 8, enc_b1, 1, e2, OUTC, nullptr, 0,
        OFF, ES, NN, 2);
    // ---- batch 3: conv3 fused (N=128 -> out[:,128:] f32) | enc3 (-> out[:,:128] f32)
    fgemm_k<<<dim3(391, 2), 256, 0, stream>>>(
        g2, g2, WT3, 1792, OUTC, 8, b3, 0, nullptr, 0, out + HALF, OUTC,
        e2, nullptr, ET2, OUTC, OUTC, 8, enc_b2, 0, nullptr, 0, out, OUTC,
        OFF, ES, NN, 1);
}

// Round 8
// 808.237 us; speedup vs baseline: 1.7295x; 1.7295x over previous
//
#include <hip/hip_runtime.h>

#define NN   50000
#define EE   800000
#define INC  128
#define OUTC 256
#define HALF 128
#define NREL 6
#define NCELL (NN * NREL)   // 300000
#define NPAD 50048          // 391*128

typedef __attribute__((ext_vector_type(4))) short s16x4;
typedef __attribute__((ext_vector_type(8))) short bf16x8;
typedef __attribute__((ext_vector_type(4))) float f32x4;

__device__ __forceinline__ float b2f(short b) {
    unsigned u = ((unsigned)(unsigned short)b) << 16;
    return __uint_as_float(u);
}
__device__ __forceinline__ short f2b(float f) {
    unsigned u = __float_as_uint(f);
    unsigned r = (u + 0x7fffu + ((u >> 16) & 1u)) >> 16;   // RNE
    return (short)r;
}

__device__ __forceinline__ void gload16(const void* g, void* l) {
    __builtin_amdgcn_global_load_lds(
        (const __attribute__((address_space(1))) void*)g,
        (__attribute__((address_space(3))) void*)l, 16, 0, 0);
}

// ---------------- CSR build ----------------
__global__ __launch_bounds__(256) void count_k(const int* __restrict__ dst,
                                               const int* __restrict__ et,
                                               int* __restrict__ cnt) {
    int e = blockIdx.x * 256 + threadIdx.x;
    if (e < EE) atomicAdd(&cnt[dst[e] * NREL + et[e]], 1);
}

__global__ __launch_bounds__(256) void scanA_k(const int* __restrict__ cnt,
                                               int* __restrict__ off,
                                               int* __restrict__ bsum, int n) {
    __shared__ int sh[256];
    int t = threadIdx.x;
    int base = blockIdx.x * 512 + t * 2;
    int v0 = (base < n) ? cnt[base] : 0;
    int v1 = (base + 1 < n) ? cnt[base + 1] : 0;
    int s = v0 + v1;
    sh[t] = s; __syncthreads();
    for (int o = 1; o < 256; o <<= 1) {
        int u = (t >= o) ? sh[t - o] : 0;
        __syncthreads();
        sh[t] += u;
        __syncthreads();
    }
    int excl = sh[t] - s;
    if (base < n)     off[base]     = excl;
    if (base + 1 < n) off[base + 1] = excl + v0;
    if (t == 255) bsum[blockIdx.x] = sh[255];
}

__global__ __launch_bounds__(1024) void scanB_k(int* __restrict__ bsum, int nb) {
    __shared__ int sh[1024];
    int t = threadIdx.x;
    int s = (t < nb) ? bsum[t] : 0;
    sh[t] = s; __syncthreads();
    for (int o = 1; o < 1024; o <<= 1) {
        int u = (t >= o) ? sh[t - o] : 0;
        __syncthreads();
        sh[t] += u;
        __syncthreads();
    }
    if (t < nb) bsum[t] = sh[t] - s;
}

__global__ __launch_bounds__(256) void scanC_k(int* __restrict__ off,
                                               const int* __restrict__ bsum, int n) {
    int i = blockIdx.x * 256 + threadIdx.x;
    if (i < n) off[i] += bsum[i >> 9];
    if (i == 0) off[n] = EE;
}

__global__ __launch_bounds__(256) void copyint_k(const int* __restrict__ a,
                                                 int* __restrict__ b, int n) {
    int i = blockIdx.x * 256 + threadIdx.x;
    if (i < n) b[i] = a[i];
}

__global__ __launch_bounds__(256) void fill_k(const int* __restrict__ src,
                                              const int* __restrict__ dst,
                                              const int* __restrict__ et,
                                              int* __restrict__ cur,
                                              int* __restrict__ es) {
    int e = blockIdx.x * 256 + threadIdx.x;
    if (e < EE) {
        int key = dst[e] * NREL + et[e];
        int p = atomicAdd(&cur[key], 1);
        es[p] = src[e];
    }
}

// ---------------- casts ----------------
__global__ __launch_bounds__(256) void cast_x_k(const float* __restrict__ x,
                                                short* __restrict__ xb, int n4) {
    int i = blockIdx.x * 256 + threadIdx.x;
    if (i < n4) {
        float4 v = ((const float4*)x)[i];
        s16x4 o;
        o[0] = f2b(v.x); o[1] = f2b(v.y); o[2] = f2b(v.z); o[3] = f2b(v.w);
        ((s16x4*)xb)[i] = o;
    }
}

// WT[Ncols][Ktot] = [root; W]^T  (bf16) — R0-verified layout.
__global__ __launch_bounds__(256) void wtcat_k(const float* __restrict__ root,
                                               const float* __restrict__ W,
                                               int K0, int Ktot, int Ncols,
                                               short* __restrict__ WT) {
    int i = blockIdx.x * 256 + threadIdx.x;
    if (i >= Ncols * Ktot) return;
    int n = i / Ktot, k = i - n * Ktot;
    float v = (k < K0) ? root[(size_t)k * Ncols + n]
                       : W[(size_t)(k - K0) * Ncols + n];
    WT[(size_t)n * Ktot + k] = f2b(v);
}

// ---------------- fused relation-tile gather-GEMM (dual-problem) ----------------
// 512 threads, 8 waves.  C[M,BN] = [A0 | AG_0..AG_5] @ WT^T (+bias,+relu).
// Phase p=0: self tile A0[128][D] staged via global_load_lds.
// Phase p>=1: AG_rel[128][D] tile computed ONCE per relation by a CSR edge loop
//   (each edge = one full contiguous D-row read of X, L3-resident, single pass),
//   reg-staged ds_write.  Then D/32 MFMA K-steps consume the tile.
// AG swizzle: chunk slot = chunk ^ (row&7) -> frag reads 2-way (free);
// Bs keeps the proven ACH swizzle.  Epilogue: LDS slab, full-line 16B stores.
// Problem 2 (blockIdx.y==1) is the encoder layer: nph=1 -> pure-GEMM path.
#define ACH(R, q) ((((R) << 2) | ((q) ^ ((R) & 3) ^ (((R) >> 2) & 1))) * 8)

template<int BN, int DSH>
__global__ __launch_bounds__(512) void fconv_k(
    const short* __restrict__ A01, const short* __restrict__ X1,
    const short* __restrict__ B1, int nph1,
    const float* __restrict__ bias1, int relu1,
    short* __restrict__ Cb1, int ldcb1, float* __restrict__ Cf1, int ldcf1,
    const short* __restrict__ A02, const short* __restrict__ X2,
    const short* __restrict__ B2, int nph2,
    const float* __restrict__ bias2, int relu2,
    short* __restrict__ Cb2, int ldcb2, float* __restrict__ Cf2, int ldcf2,
    const int* __restrict__ off, const int* __restrict__ es, int M) {
    constexpr int D = 1 << DSH;          // 128 or 256
    constexpr int NCH = D >> 3;          // 16B chunks per row: 16 or 32
    constexpr int KPP = D >> 5;          // K-steps per phase: 4 or 8
    constexpr int MT = (BN == 256) ? 4 : 2;
    __shared__ __align__(16) short AG[128 * D];   // 32 or 64 KB
    __shared__ __align__(16) short Bs[BN * 32];   // 8 or 16 KB
    const int tid = threadIdx.x;
    const int wave = tid >> 6, lane = tid & 63;
    const int l16 = lane & 15, quad = lane >> 4;
    const int wm = (BN == 256) ? (wave & 1) * 64 : (wave & 3) * 32;
    const int wn = (BN == 256) ? (wave >> 1) * 64 : (wave >> 2) * 64;
    const int bm = blockIdx.x * 128;

    const short *A0, *X, *BT; const float* bias;
    int nph, relu; short* Cb; int ldcb; float* Cf; int ldcf;
    if (blockIdx.y == 0) {
        A0 = A01; X = X1; BT = B1; nph = nph1; bias = bias1; relu = relu1;
        Cb = Cb1; ldcb = ldcb1; Cf = Cf1; ldcf = ldcf1;
    } else {
        A0 = A02; X = X2; BT = B2; nph = nph2; bias = bias2; relu = relu2;
        Cb = Cb2; ldcb = ldcb2; Cf = Cf2; ldcf = ldcf2;
    }
    const int Kt = nph << DSH;           // WT row stride

    f32x4 acc[MT][4];
    #pragma unroll
    for (int i = 0; i < MT; ++i)
        #pragma unroll
        for (int j = 0; j < 4; ++j)
            acc[i][j] = (f32x4)0.f;

    for (int ph = 0; ph < nph; ++ph) {
        if (ph == 0) {
            // self tile: A0[bm..bm+128][0..D], pre-swizzled source cols
            #pragma unroll
            for (int it = 0; it < (128 * NCH) / 512; ++it) {
                int s = tid + it * 512;
                int row = s >> (DSH - 3), ch = s & (NCH - 1);
                gload16(A0 + (size_t)(bm + row) * D + (ch ^ (row & 7)) * 8,
                        AG + (size_t)s * 8);
            }
        } else {
            // gather tile: AG[row][slot] = mean over edges of X[src] chunk slot^(row&7)
            int rel = ph - 1;
            int grp = tid >> (DSH - 3), ln = tid & (NCH - 1);
            constexpr int RPB = 512 >> (DSH - 3);   // rows in flight: 32 or 16
            for (int rr = 0; rr < 128 / RPB; ++rr) {
                int row = rr * RPB + grp;
                int node = bm + row;
                int beg = 0, end = 0;
                if (node < M) {
                    int cell = node * NREL + rel;
                    beg = off[cell]; end = off[cell + 1];
                }
                const short* Xb = X + (ln ^ (row & 7)) * 8;
                float a0 = 0.f, a1 = 0.f, a2 = 0.f, a3 = 0.f;
                float a4 = 0.f, a5 = 0.f, a6 = 0.f, a7 = 0.f;
                int j = beg;
                for (; j + 1 < end; j += 2) {
                    bf16x8 v = *(const bf16x8*)(Xb + ((size_t)es[j] << DSH));
                    bf16x8 w = *(const bf16x8*)(Xb + ((size_t)es[j + 1] << DSH));
                    a0 += b2f(v[0]) + b2f(w[0]);
                    a1 += b2f(v[1]) + b2f(w[1]);
                    a2 += b2f(v[2]) + b2f(w[2]);
                    a3 += b2f(v[3]) + b2f(w[3]);
                    a4 += b2f(v[4]) + b2f(w[4]);
                    a5 += b2f(v[5]) + b2f(w[5]);
                    a6 += b2f(v[6]) + b2f(w[6]);
                    a7 += b2f(v[7]) + b2f(w[7]);
                }
                if (j < end) {
                    bf16x8 v = *(const bf16x8*)(Xb + ((size_t)es[j] << DSH));
                    a0 += b2f(v[0]); a1 += b2f(v[1]);
                    a2 += b2f(v[2]); a3 += b2f(v[3]);
                    a4 += b2f(v[4]); a5 += b2f(v[5]);
                    a6 += b2f(v[6]); a7 += b2f(v[7]);
                }
                float inv = (end > beg) ? 1.f / (float)(end - beg) : 0.f;
                bf16x8 o;
                o[0] = f2b(a0 * inv); o[1] = f2b(a1 * inv);
                o[2] = f2b(a2 * inv); o[3] = f2b(a3 * inv);
                o[4] = f2b(a4 * inv); o[5] = f2b(a5 * inv);
                o[6] = f2b(a6 * inv); o[7] = f2b(a7 * inv);
                *(bf16x8*)&AG[row * D + ln * 8] = o;
            }
        }
        for (int kk = 0; kk < KPP; ++kk) {
            int k0 = (ph << DSH) + kk * 32;
            #pragma unroll
            for (int it = 0; it < (BN * 4) / 512; ++it) {
                int s = tid + it * 512;
                int r = s >> 2, c = (s & 3) ^ (r & 3) ^ ((r >> 2) & 1);
                gload16(BT + (size_t)r * Kt + k0 + c * 8, Bs + (size_t)s * 8);
            }
            __syncthreads();       // AG (first kk) + Bs visible; vmcnt drained
            bf16x8 af[MT], bf[4];
            #pragma unroll
            for (int mt = 0; mt < MT; ++mt) {
                int row = wm + mt * 16 + l16;
                int ch = ((kk << 2) + quad) ^ (row & 7);
                af[mt] = *(const bf16x8*)&AG[row * D + ch * 8];
            }
            #pragma unroll
            for (int nt = 0; nt < 4; ++nt)
                bf[nt] = *(const bf16x8*)&Bs[ACH(wn + nt * 16 + l16, quad)];
            #pragma unroll
            for (int mt = 0; mt < MT; ++mt)
                #pragma unroll
                for (int nt = 0; nt < 4; ++nt)
                    acc[mt][nt] = __builtin_amdgcn_mfma_f32_16x16x32_bf16(
                        af[mt], bf[nt], acc[mt][nt], 0, 0, 0);
            __syncthreads();       // all reads done before next stage
        }
    }

    float bv[4];
    #pragma unroll
    for (int nt = 0; nt < 4; ++nt)
        bv[nt] = bias ? bias[wn + nt * 16 + l16] : 0.f;

    constexpr int SR = (BN == 256) ? 32 : 64;    // slab rows per mt-pass
    const int srb = ((BN == 256) ? (wave & 1) : (wave & 3)) * 16 + quad * 4;
    if (Cb) {
        short* Es = AG;                          // [SR][BN] bf16 slab
        #pragma unroll
        for (int mt = 0; mt < MT; ++mt) {
            __syncthreads();
            #pragma unroll
            for (int nt = 0; nt < 4; ++nt) {
                int sc = wn + nt * 16 + l16;
                #pragma unroll
                for (int r = 0; r < 4; ++r) {
                    float v = acc[mt][nt][r] + bv[nt];
                    if (relu) v = fmaxf(v, 0.f);
                    Es[(srb + r) * BN + sc] = f2b(v);
                }
            }
            __syncthreads();
            #pragma unroll
            for (int h = 0; h < (SR * (BN / 8)) / 512; ++h) {
                int c = tid + h * 512;
                int rr = c / (BN / 8), cc = c & (BN / 8 - 1);
                int grow = bm + (rr >> 4) * ((BN == 256) ? 64 : 32) + mt * 16 + (rr & 15);
                if (grow < M)
                    *(bf16x8*)(Cb + (size_t)grow * ldcb + cc * 8) =
                        *(const bf16x8*)&Es[rr * BN + cc * 8];
            }
        }
    } else {
        float* Ef = (float*)AG;                  // [SR][BN] f32 slab
        #pragma unroll
        for (int mt = 0; mt < MT; ++mt) {
            __syncthreads();
            #pragma unroll
            for (int nt = 0; nt < 4; ++nt) {
                int sc = wn + nt * 16 + l16;
                #pragma unroll
                for (int r = 0; r < 4; ++r) {
                    float v = acc[mt][nt][r] + bv[nt];
                    if (relu) v = fmaxf(v, 0.f);
                    Ef[(srb + r) * BN + sc] = v;
                }
            }
            __syncthreads();
            #pragma unroll
            for (int h = 0; h < (SR * (BN / 4)) / 512; ++h) {
                int c = tid + h * 512;
                int rr = c / (BN / 4), cc = c & (BN / 4 - 1);
                int grow = bm + (rr >> 4) * ((BN == 256) ? 64 : 32) + mt * 16 + (rr & 15);
                if (grow < M)
                    *(float4*)(Cf + (size_t)grow * ldcf + cc * 4) =
                        *(const float4*)&Ef[rr * BN + cc * 4];
            }
        }
    }
}

// ---------------- host ----------------
extern "C" void kernel_launch(void* const* d_in, const int* in_sizes, int n_in,
                              void* d_out, int out_size, void* d_ws, size_t ws_size,
                              hipStream_t stream) {
    const float* x      = (const float*)d_in[0];
    const int*   ei     = (const int*)d_in[1];
    const int*   srcv   = ei;
    const int*   dstv   = ei + EE;
    const int*   et     = (const int*)d_in[2];
    const float* enc_w0 = (const float*)d_in[3];
    const float* enc_b0 = (const float*)d_in[4];
    const float* enc_w1 = (const float*)d_in[5];
    const float* enc_b1 = (const float*)d_in[6];
    const float* enc_w2 = (const float*)d_in[7];
    const float* enc_b2 = (const float*)d_in[8];
    const float* W1     = (const float*)d_in[9];
    const float* root1  = (const float*)d_in[10];
    const float* b1     = (const float*)d_in[11];
    const float* W2     = (const float*)d_in[12];
    const float* root2  = (const float*)d_in[13];
    const float* b2     = (const float*)d_in[14];
    const float* W3     = (const float*)d_in[15];
    const float* root3  = (const float*)d_in[16];
    const float* b3     = (const float*)d_in[17];
    float* out = (float*)d_out;

    char* p = (char*)d_ws;
    auto alloc = [&](size_t bytes) -> char* {
        char* r = p; p += (bytes + 255) & ~(size_t)255; return r;
    };
    short* xb  = (short*)alloc((size_t)NPAD * INC * 2);
    short* g1  = (short*)alloc((size_t)NPAD * OUTC * 2);
    short* g2  = (short*)alloc((size_t)NPAD * OUTC * 2);
    short* e1  = (short*)alloc((size_t)NPAD * OUTC * 2);
    short* e2  = (short*)alloc((size_t)NPAD * OUTC * 2);
    short* WT1 = (short*)alloc((size_t)OUTC * 896 * 2);    // [root1; W1]^T
    short* WT2 = (short*)alloc((size_t)OUTC * 1792 * 2);   // [root2; W2]^T
    short* WT3 = (short*)alloc((size_t)HALF * 1792 * 2);   // [root3; W3]^T
    short* ET0 = (short*)alloc((size_t)OUTC * INC * 2);
    short* ET1 = (short*)alloc((size_t)OUTC * OUTC * 2);
    short* ET2 = (short*)alloc((size_t)HALF * OUTC * 2);
    int* CNT  = (int*)alloc((size_t)NCELL * 4);
    int* OFF  = (int*)alloc((size_t)(NCELL + 1) * 4);
    int* CUR  = (int*)alloc((size_t)NCELL * 4);
    int* ES   = (int*)alloc((size_t)EE * 4);
    int* BSUM = (int*)alloc(1024 * 4);

    // ---- CSR build (once; edge structure shared by all 3 layers)
    hipMemsetAsync(CNT, 0, (size_t)NCELL * 4, stream);
    count_k<<<EE / 256, 256, 0, stream>>>(dstv, et, CNT);
    int nbA = (NCELL + 511) / 512;
    scanA_k<<<nbA, 256, 0, stream>>>(CNT, OFF, BSUM, NCELL);
    scanB_k<<<1, 1024, 0, stream>>>(BSUM, nbA);
    scanC_k<<<(NCELL + 255) / 256, 256, 0, stream>>>(OFF, BSUM, NCELL);
    copyint_k<<<(NCELL + 255) / 256, 256, 0, stream>>>(OFF, CUR, NCELL);
    fill_k<<<EE / 256, 256, 0, stream>>>(srcv, dstv, et, CUR, ES);

    // ---- weight transposes + input cast
    cast_x_k<<<(NN * INC / 4 + 255) / 256, 256, 0, stream>>>(x, xb, NN * INC / 4);
    wtcat_k<<<(OUTC * 896 + 255) / 256, 256, 0, stream>>>(root1, W1, INC, 896, OUTC, WT1);
    wtcat_k<<<(OUTC * 1792 + 255) / 256, 256, 0, stream>>>(root2, W2, OUTC, 1792, OUTC, WT2);
    wtcat_k<<<(HALF * 1792 + 255) / 256, 256, 0, stream>>>(root3, W3, OUTC, 1792, HALF, WT3);
    wtcat_k<<<(OUTC * INC + 255) / 256, 256, 0, stream>>>(enc_w0, nullptr, INC, INC, OUTC, ET0);
    wtcat_k<<<(OUTC * OUTC + 255) / 256, 256, 0, stream>>>(enc_w1, nullptr, OUTC, OUTC, OUTC, ET1);
    wtcat_k<<<(HALF * OUTC + 255) / 256, 256, 0, stream>>>(enc_w2, nullptr, OUTC, OUTC, HALF, ET2);

    // ---- layer 1: conv1 (D=128, BN=256, 7 phases) | enc1 (D=128, 1 phase)
    fconv_k<256, 7><<<dim3(391, 2), 512, 0, stream>>>(
        xb, xb, WT1, 7, b1, 1, g1, OUTC, nullptr, 0,
        xb, nullptr, ET0, 1, enc_b0, 1, e1, OUTC, nullptr, 0,
        OFF, ES, NN);
    // ---- layer 2: conv2 (D=256, BN=256, 7 phases) | enc2 (D=256, 1 phase)
    fconv_k<256, 8><<<dim3(391, 2), 512, 0, stream>>>(
        g1, g1, WT2, 7, b2, 1, g2, OUTC, nullptr, 0,
        e1, nullptr, ET1, 1, enc_b1, 1, e2, OUTC, nullptr, 0,
        OFF, ES, NN);
    // ---- layer 3: conv3 (D=256, BN=128 -> out[:,128:]) | enc3 (-> out[:,:128])
    fconv_k<128, 8><<<dim3(391, 2), 512, 0, stream>>>(
        g2, g2, WT3, 7, b3, 0, nullptr, 0, out + HALF, OUTC,
        e2, nullptr, ET2, 1, enc_b2, 0, nullptr, 0, out, OUTC,
        OFF, ES, NN);
}